// Round 7
// baseline (838.348 us; speedup 1.0000x reference)
//
#include <hip/hip_runtime.h>
#include <hip/hip_fp16.h>

// 3-layer GCN (fp32 compute): bucketed CSR build + gemm1 + fused
// (aggregate -> GEMM) pairs.
// Round 13: (1) REVERT r12's dual-node gather interleave (hurt: VGPR 28->44,
// occupancy 80->42%, ag2 149->210 us) -- back to r10's sequential 8-deep
// chunks. (2) NEW: per-node src-SORTED neighbor lists (one-time insertion
// sort in k_prep). All CUs sweep src space ~in lockstep (degrees ~Poisson 16)
// -> the hot src window fits per-XCD L2 -> L2 hit rate up, FETCH down from
// the 8x-table 406 MB. Aggregation is order-invariant. Sorted col reused by
// ag3/agf. CSR build stays r12 (padded buckets, no bhist/bscan).

#define N_NODES 200000
#define N_EDGES 3200000
#define NBUCK 782            // ceil(200000/256)
#define BCAP 5120            // padded bucket capacity (mean 4096, +16 sigma)

static_assert(N_NODES % 64 == 0, "tiling");
static_assert((NBUCK - 1) * 256 < N_NODES && NBUCK * 256 >= N_NODES, "buckets");

typedef unsigned int u32;
typedef _Float16 f16;
typedef __attribute__((ext_vector_type(8))) _Float16 f16x8;
typedef __attribute__((ext_vector_type(4))) _Float16 f16x4;
typedef __attribute__((ext_vector_type(4))) float f32x4;
typedef __attribute__((ext_vector_type(2))) float f32x2;

// ------------- chunked scatter: entries[b*BCAP+p] = (src<<8)|dst_local ------
// Block-local histogram, one global atomicAdd per (block,bucket) reserves a
// range in the bucket's padded segment. No global prefix scan needed.

__global__ __launch_bounds__(256) void k_scatter(const int* __restrict__ src,
                                                 const int* __restrict__ dst,
                                                 int* __restrict__ bcur,
                                                 u32* __restrict__ entries) {
    __shared__ int lh[NBUCK];
    __shared__ int base[NBUCK];
    __shared__ int lcur[NBUCK];
    int t = threadIdx.x;
    for (int b = t; b < NBUCK; b += 256) lh[b] = 0;
    __syncthreads();
    long e0 = (long)blockIdx.x * 8192;
    for (int k = 0; k < 32; ++k) {
        long e = e0 + k * 256 + t;
        if (e < N_EDGES) atomicAdd(&lh[dst[e] >> 8], 1);
    }
    __syncthreads();
    for (int b = t; b < NBUCK; b += 256) {
        base[b] = lh[b] ? atomicAdd(&bcur[b], lh[b]) : 0;
        lcur[b] = 0;
    }
    __syncthreads();
    for (int k = 0; k < 32; ++k) {
        long e = e0 + k * 256 + t;
        if (e < N_EDGES) {
            int d = dst[e];
            int bkt = d >> 8;
            int p = base[bkt] + atomicAdd(&lcur[bkt], 1);
            p = p < BCAP ? p : BCAP - 1;  // defensive (cannot trigger w/ fixed input)
            entries[(size_t)bkt * BCAP + p] = ((u32)src[e] << 8) | (u32)(d & 255);
        }
    }
}

// --- per-bucket prep: deg/rs/re/dinv + col fill + per-node src-sort ---------

__global__ __launch_bounds__(256) void k_prep(const u32* __restrict__ entries,
                                              const int* __restrict__ bcur,
                                              int* __restrict__ rs,
                                              int* __restrict__ re,
                                              float* __restrict__ dinv,
                                              int* __restrict__ col) {
    __shared__ int lh[256];
    __shared__ int sc[256];
    __shared__ int cur[256];
    const int b = blockIdx.x, t = threadIdx.x;
    int cnt = bcur[b];
    cnt = cnt < BCAP ? cnt : BCAP;  // defensive
    const u32* ent = entries + (size_t)b * BCAP;
    lh[t] = 0;
    __syncthreads();
    for (int i = t; i < cnt; i += 256) atomicAdd(&lh[ent[i] & 255], 1);
    __syncthreads();
    int my = lh[t];
    sc[t] = my;
    __syncthreads();
    for (int o = 1; o < 256; o <<= 1) {
        int v = (t >= o) ? sc[t - o] : 0;
        __syncthreads();
        sc[t] += v;
        __syncthreads();
    }
    int excl = sc[t] - my;
    int node = b * 256 + t;
    if (node < N_NODES) {
        rs[node] = b * BCAP + excl;
        re[node] = b * BCAP + excl + my;
        dinv[node] = rsqrtf((float)(my + 1));  // +1 self-loop
    }
    cur[t] = b * BCAP + excl;
    __syncthreads();
    for (int i = t; i < cnt; i += 256) {
        u32 en = ent[i];
        int p = atomicAdd(&cur[en & 255], 1);
        col[p] = (int)(en >> 8);
    }
    __syncthreads();  // all col writes visible (same CU, write-through L1)

    // per-node src-sort (gather locality; sum is order-invariant).
    // deg ~ Poisson(16): P(deg>48) ~ 1e-11/node -- unsorted tail is harmless.
    if (node < N_NODES && my > 1) {
        const int base = b * BCAP + excl;
        const int nbuf = my < 48 ? my : 48;
        int buf[48];
        for (int i = 0; i < nbuf; ++i) buf[i] = col[base + i];
        for (int i = 1; i < nbuf; ++i) {
            int v = buf[i], j = i - 1;
            while (j >= 0 && buf[j] > v) { buf[j + 1] = buf[j]; --j; }
            buf[j + 1] = v;
        }
        for (int i = 0; i < nbuf; ++i) col[base + i] = buf[i];
    }
}

// ------- W1 pre-split/transpose: Wth/Wtl[f][k] f16 hi/lo, k-major -----------

__global__ __launch_bounds__(256) void k_prepw(const float* __restrict__ W,
                                               f16* __restrict__ Wth,
                                               f16* __restrict__ Wtl) {
    int t = blockIdx.x * 256 + threadIdx.x;  // 0..32767
    int k = t >> 7;                          // 0..255 (tail rows 256/257 stay fp32)
    int f = t & 127;
    float w = W[k * 128 + f];
    f16 hi = (f16)w;
    f16 lo = (f16)(w - (float)hi);
    Wth[f * 256 + k] = hi;
    Wtl[f * 256 + k] = lo;
}

// ------- W2 pre-split/transpose: [128][64] -> hi/lo f16 [64][128] k-major ----

__global__ __launch_bounds__(256) void k_prepw2(const float* __restrict__ W2,
                                                f16* __restrict__ Wh,
                                                f16* __restrict__ Wl) {
    int t = blockIdx.x * 256 + threadIdx.x;  // 0..8191
    int k = t >> 6;                          // 0..127
    int f = t & 63;
    float w = W2[k * 64 + f];
    f16 hi = (f16)w;
    Wh[f * 128 + k] = hi;
    Wl[f * 128 + k] = (f16)(w - (float)hi);
}

// ------- GEMM layer 1 (MFMA): [N,258]x[258,128], epilogue g = dinv*h -> fp16
// 1024 threads = 16 waves, 256 nodes/block, 16 nodes/wave. W hi+lo in LDS
// (128 KB, XOR-swizzled), staged once; X fragments global->reg (8 consecutive
// floats/lane); no per-K-step barriers. 3-term split-f16 = ~fp32 precision.

__global__ __launch_bounds__(1024) void k_gemm1(const float* __restrict__ X,
                                                const float* __restrict__ hist,
                                                const float* __restrict__ subg,
                                                const float* __restrict__ W,
                                                const f16* __restrict__ Wth,
                                                const f16* __restrict__ Wtl,
                                                const float* __restrict__ dinv,
                                                __half2* __restrict__ g1) {
    __shared__ f16 Ws[2][128 * 256];   // [hi/lo][row*256+k], byte^((row&7)<<4)
    const int t = threadIdx.x;

    // ---- stage W once (swizzled writes, coalesced global reads) ----
    {
        const int r = t >> 3;          // feat row 0..127
        const int seg = t & 7;         // 32 halves each
        const f16* gh = Wth + r * 256 + seg * 32;
        const f16* gl = Wtl + r * 256 + seg * 32;
        const int sw = (r & 7) << 4;
        const int base = r * 512 + seg * 64;   // byte offset, 16B-granular
        char* wsh = (char*)&Ws[0][0];
        char* wsl = (char*)&Ws[1][0];
#pragma unroll
        for (int q = 0; q < 4; ++q) {
            *(f16x8*)(wsh + ((base + q * 16) ^ sw)) = *(const f16x8*)(gh + q * 8);
            *(f16x8*)(wsl + ((base + q * 16) ^ sw)) = *(const f16x8*)(gl + q * 8);
        }
    }

    const int wv = t >> 6;          // wave 0..15
    const int l = t & 63;
    const int l15 = l & 15;         // node within wave / D column
    const int lk = l >> 4;          // k-chunk 0..3 (8 halves each)
    const int nb = blockIdx.x * 256;
    const int node = nb + wv * 16 + l15;
    const int xrow = node < N_NODES ? node : N_NODES - 1;  // clamp (stores guarded)
    const float* xbase = X + (size_t)xrow * 256 + lk * 8;

    f32x4 acc[8];
#pragma unroll
    for (int fb = 0; fb < 8; ++fb) acc[fb] = (f32x4){0.f, 0.f, 0.f, 0.f};

    // prefetch K-tile 0 (in flight across the staging barrier)
    float4 pa = *(const float4*)(xbase + 0);
    float4 pb = *(const float4*)(xbase + 4);

    __syncthreads();  // W staged -- the only barrier

    const char* wsh = (const char*)&Ws[0][0];
    const char* wsl = (const char*)&Ws[1][0];
    const int sw = (l15 & 7) << 4;  // row&7 == l15&7 for every fb

    for (int kc = 0; kc < 256; kc += 32) {
        float xs[8] = {pa.x, pa.y, pa.z, pa.w, pb.x, pb.y, pb.z, pb.w};
        if (kc + 32 < 256) {  // issue next-tile loads before compute
            pa = *(const float4*)(xbase + kc + 32);
            pb = *(const float4*)(xbase + kc + 36);
        }
        union { f16 h[8]; f16x8 v; } H, L;
#pragma unroll
        for (int i = 0; i < 8; ++i) {
            f16 h = (f16)xs[i];
            H.h[i] = h;
            L.h[i] = (f16)(xs[i] - (float)h);
        }
        f16x8 xh = H.v, xl = L.v;

        const int koff = ((kc + lk * 8) * 2) ^ sw;  // swizzled within-row byte off
#pragma unroll
        for (int fb = 0; fb < 8; ++fb) {
            const int off = (fb * 16 + l15) * 512 + koff;
            f16x8 wh = *(const f16x8*)(wsh + off);
            f16x8 wl = *(const f16x8*)(wsl + off);
            acc[fb] = __builtin_amdgcn_mfma_f32_16x16x32_f16(wh, xh, acc[fb], 0, 0, 0);
            acc[fb] = __builtin_amdgcn_mfma_f32_16x16x32_f16(wh, xl, acc[fb], 0, 0, 0);
            acc[fb] = __builtin_amdgcn_mfma_f32_16x16x32_f16(wl, xh, acc[fb], 0, 0, 0);
        }
    }

    // epilogue: K tail rows 256 (hist), 257 (subg) in exact fp32; scale dinv.
    const bool ok = node < N_NODES;
    const float hh = hist[xrow];
    const float ss = subg[xrow];
    const float dv = dinv[xrow];
    char* orow = (char*)g1 + (size_t)node * 256;
#pragma unroll
    for (int fb = 0; fb < 8; ++fb) {
        const int f0 = fb * 16 + lk * 4;  // 4 consecutive feats per lane
        float4 w6 = *(const float4*)(W + 256 * 128 + f0);
        float4 w7 = *(const float4*)(W + 257 * 128 + f0);
        union { f16 h[4]; float2 v; } o;
        o.h[0] = (f16)((acc[fb][0] + hh * w6.x + ss * w7.x) * dv);
        o.h[1] = (f16)((acc[fb][1] + hh * w6.y + ss * w7.y) * dv);
        o.h[2] = (f16)((acc[fb][2] + hh * w6.z + ss * w7.z) * dv);
        o.h[3] = (f16)((acc[fb][3] + hh * w6.w + ss * w7.w) * dv);
        if (ok) *(float2*)(orow + fb * 32 + lk * 8) = o.v;
    }
}

// ------- fused agg1 + gemm2: h2 = relu(dinv*(sum g1)+b1); g2 = dinv*(h2@W2)
// 1024 threads, 64 nodes/block. Phase A (r10 form): lane owns 4 feats (f16x4,
// 8 B loads), 2 nodes sequentially, 8-deep chunks; src-sorted col gives L2
// locality. Phase B: 16 waves, one 16x16 MFMA tile each (K=128, 3-term split).

__global__ __launch_bounds__(1024) void k_ag2(const __half2* __restrict__ g,
                                              const int* __restrict__ rs,
                                              const int* __restrict__ re,
                                              const int* __restrict__ col,
                                              const float* __restrict__ dinv,
                                              const float* __restrict__ bias,
                                              const f16* __restrict__ W2hg,
                                              const f16* __restrict__ W2lg,
                                              __half2* __restrict__ g2) {
    __shared__ f16 Xh[64][136];
    __shared__ f16 Xl[64][136];
    __shared__ f16 Wh[64][136];
    __shared__ f16 Wl[64][136];
    const int t = threadIdx.x;
    const int nb = blockIdx.x * 64;

    // stage W2 hi/lo (once)
    {
        const int r = t >> 4;          // 0..63
        const int sg = (t & 15) * 8;   // 8 halves
        *(f16x8*)&Wh[r][sg] = *(const f16x8*)(W2hg + r * 128 + sg);
        *(f16x8*)&Wl[r][sg] = *(const f16x8*)(W2lg + r * 128 + sg);
    }

    // ---- phase A: aggregate. lane owns feats 4*ln..+3 of 2 nodes ----
    const int wv = t >> 6;
    const int l = t & 63;
    const int hf = l >> 5;         // 0/1
    const int ln = l & 31;         // f16x4 index within row (32 per row)
    const f16x4* gp = (const f16x4*)g;   // row stride 32 f16x4
    const float4 b4 = *(const float4*)(bias + ln * 4);
    for (int i = 0; i < 2; ++i) {
        const int nloc = wv * 4 + hf * 2 + i;
        const int node = nb + nloc;
        f32x4 a = (f32x4){0.f, 0.f, 0.f, 0.f};
        int idx = rs[node];
        const int e = re[node];
        for (; idx + 8 <= e; idx += 8) {
            u32 off[8];
            f16x4 h[8];
#pragma unroll
            for (int u = 0; u < 8; ++u) off[u] = ((u32)col[idx + u] << 5) + ln;
#pragma unroll
            for (int u = 0; u < 8; ++u) h[u] = gp[off[u]];
#pragma unroll
            for (int u = 0; u < 8; ++u) a += __builtin_convertvector(h[u], f32x4);
        }
        for (; idx < e; ++idx)
            a += __builtin_convertvector(gp[((u32)col[idx] << 5) + ln], f32x4);
        f32x4 fs = __builtin_convertvector(gp[((u32)node << 5) + ln], f32x4);
        const float di = dinv[node];
        float v0 = fmaxf(di * (a[0] + fs[0]) + b4.x, 0.f);
        float v1 = fmaxf(di * (a[1] + fs[1]) + b4.y, 0.f);
        float v2 = fmaxf(di * (a[2] + fs[2]) + b4.z, 0.f);
        float v3 = fmaxf(di * (a[3] + fs[3]) + b4.w, 0.f);
        f16 h0 = (f16)v0, h1 = (f16)v1, h2 = (f16)v2, h3 = (f16)v3;
        f16x4 hi = {h0, h1, h2, h3};
        f16x4 lo = {(f16)(v0 - (float)h0), (f16)(v1 - (float)h1),
                    (f16)(v2 - (float)h2), (f16)(v3 - (float)h3)};
        *(f16x4*)&Xh[nloc][ln * 4] = hi;
        *(f16x4*)&Xl[nloc][ln * 4] = lo;
    }
    __syncthreads();

    // ---- phase B: 16 waves x one 16x16 MFMA tile, K=128 ----
    const int l15 = l & 15;
    const int lk = l >> 4;
    const int nw = wv & 3;    // node tile
    const int fw = wv >> 2;   // feat tile
    f32x4 acc = (f32x4){0.f, 0.f, 0.f, 0.f};
#pragma unroll
    for (int kc = 0; kc < 128; kc += 32) {
        f16x8 xh = *(const f16x8*)&Xh[nw * 16 + l15][kc + lk * 8];
        f16x8 xl = *(const f16x8*)&Xl[nw * 16 + l15][kc + lk * 8];
        f16x8 wh = *(const f16x8*)&Wh[fw * 16 + l15][kc + lk * 8];
        f16x8 wl = *(const f16x8*)&Wl[fw * 16 + l15][kc + lk * 8];
        acc = __builtin_amdgcn_mfma_f32_16x16x32_f16(wh, xh, acc, 0, 0, 0);
        acc = __builtin_amdgcn_mfma_f32_16x16x32_f16(wh, xl, acc, 0, 0, 0);
        acc = __builtin_amdgcn_mfma_f32_16x16x32_f16(wl, xh, acc, 0, 0, 0);
    }
    const int node = nb + nw * 16 + l15;
    const float dv = dinv[node];
    union { f16 h[4]; float2 v; } o;
#pragma unroll
    for (int r = 0; r < 4; ++r) o.h[r] = (f16)(acc[r] * dv);
    *(float2*)((char*)g2 + (size_t)node * 128 + fw * 32 + lk * 8) = o.v;
}

// ------- fused agg2 + gemm3: h3 = relu(dinv*(sum g2)+b2); g3 = dinv*(h3@W3)
// 256 threads, 32 nodes/block. Phase A (r10 form): lane owns 4 feats (f16x4),
// 2 nodes sequentially. Phase B: thread (node,f) 64-MAC dot.

__global__ __launch_bounds__(256) void k_ag3(const __half2* __restrict__ g,
                                             const int* __restrict__ rs,
                                             const int* __restrict__ re,
                                             const int* __restrict__ col,
                                             const float* __restrict__ dinv,
                                             const float* __restrict__ bias,
                                             const float* __restrict__ W3,
                                             float* __restrict__ g3) {
    __shared__ float h3s[32][68];
    __shared__ float W3t[8][68];
    const int t = threadIdx.x;
    const int nb = blockIdx.x * 32;

    for (int i = t; i < 512; i += 256) {
        int k = i & 63, f = i >> 6;
        W3t[f][k] = W3[k * 8 + f];
    }

    const int wv = t >> 6;        // 0..3
    const int l = t & 63;
    const int q = l >> 4;         // 0..3: node-of-quad
    const int ln = l & 15;        // f16x4 index (16 per 64-f16 row)
    const f16x4* gp = (const f16x4*)g;   // row stride 16 f16x4
    const float4 b4 = *(const float4*)(bias + ln * 4);
    for (int i = 0; i < 2; ++i) {
        const int nloc = wv * 8 + q * 2 + i;
        const int node = nb + nloc;
        f32x4 a = (f32x4){0.f, 0.f, 0.f, 0.f};
        int idx = rs[node];
        const int e = re[node];
        for (; idx + 8 <= e; idx += 8) {
            u32 off[8];
            f16x4 h[8];
#pragma unroll
            for (int u = 0; u < 8; ++u) off[u] = ((u32)col[idx + u] << 4) + ln;
#pragma unroll
            for (int u = 0; u < 8; ++u) h[u] = gp[off[u]];
#pragma unroll
            for (int u = 0; u < 8; ++u) a += __builtin_convertvector(h[u], f32x4);
        }
        for (; idx < e; ++idx)
            a += __builtin_convertvector(gp[((u32)col[idx] << 4) + ln], f32x4);
        f32x4 fs = __builtin_convertvector(gp[((u32)node << 4) + ln], f32x4);
        const float di = dinv[node];
        float4 o;
        o.x = fmaxf(di * (a[0] + fs[0]) + b4.x, 0.f);
        o.y = fmaxf(di * (a[1] + fs[1]) + b4.y, 0.f);
        o.z = fmaxf(di * (a[2] + fs[2]) + b4.z, 0.f);
        o.w = fmaxf(di * (a[3] + fs[3]) + b4.w, 0.f);
        *(float4*)&h3s[nloc][ln * 4] = o;
    }
    __syncthreads();

    const int node = t >> 3;   // 0..31
    const int f = t & 7;
    float acc = 0.f;
#pragma unroll
    for (int k4 = 0; k4 < 16; ++k4) {
        float4 x = *(const float4*)&h3s[node][k4 * 4];
        float4 w = *(const float4*)&W3t[f][k4 * 4];
        acc += x.x * w.x + x.y * w.y + x.z * w.z + x.w * w.w;
    }
    g3[(size_t)(nb + node) * 8 + f] = dinv[nb + node] * acc;
}

// ------- fused agg3 + final: h4 = relu(dinv*(sum g3)+b3); out = h4@Wc + bc ---
// 64 nodes/block; lane c=t&3 owns float2 feats 2c..2c+1; 16-deep batches.

__global__ __launch_bounds__(256) void k_agf(const float* __restrict__ g,
                                             const int* __restrict__ rs,
                                             const int* __restrict__ re,
                                             const int* __restrict__ col,
                                             const float* __restrict__ dinv,
                                             const float* __restrict__ bias,
                                             const float* __restrict__ Wc,
                                             const float* __restrict__ bc,
                                             float* __restrict__ out) {
    __shared__ float h4s[64][10];
    __shared__ float Wcs[24];
    __shared__ float bcs[3];
    const int t = threadIdx.x;
    const int nb = blockIdx.x * 64;
    if (t < 24) Wcs[t] = Wc[t];
    if (t < 3) bcs[t] = bc[t];

    const int node = t >> 2;   // 0..63
    const int c = t & 3;       // float2 index within 8-f32 row
    const f32x2* gp = (const f32x2*)g;   // row stride 4 f32x2
    const float2 b2 = *(const float2*)(bias + c * 2);
    f32x2 a = (f32x2){0.f, 0.f};
    const int s = rs[nb + node];
    const int e = re[nb + node];
    int idx = s;
    for (; idx + 16 <= e; idx += 16) {
        u32 off[16];
        f32x2 v[16];
#pragma unroll
        for (int u = 0; u < 16; ++u) off[u] = ((u32)col[idx + u] << 2) + c;
#pragma unroll
        for (int u = 0; u < 16; ++u) v[u] = gp[off[u]];
#pragma unroll
        for (int u = 0; u < 16; ++u) a += v[u];
    }
    for (; idx + 8 <= e; idx += 8) {
        u32 off[8];
        f32x2 v[8];
#pragma unroll
        for (int u = 0; u < 8; ++u) off[u] = ((u32)col[idx + u] << 2) + c;
#pragma unroll
        for (int u = 0; u < 8; ++u) v[u] = gp[off[u]];
#pragma unroll
        for (int u = 0; u < 8; ++u) a += v[u];
    }
    for (; idx < e; ++idx) a += gp[((u32)col[idx] << 2) + c];
    a += gp[((u32)(nb + node) << 2) + c];  // self-loop
    const float di = dinv[nb + node];
    float2 o;
    o.x = fmaxf(di * a[0] + b2.x, 0.f);
    o.y = fmaxf(di * a[1] + b2.y, 0.f);
    *(float2*)&h4s[node][c * 2] = o;
    __syncthreads();

    if ((t & 3) < 3) {
        const int n2 = t >> 2;   // 0..63
        const int cc = t & 3;    // 0..2
        float o2 = bcs[cc];
#pragma unroll
        for (int k = 0; k < 8; ++k) o2 += h4s[n2][k] * Wcs[k * 3 + cc];
        out[(size_t)(nb + n2) * 3 + cc] = o2;
    }
}

// ---------------- launch -----------------------------------------------------

extern "C" void kernel_launch(void* const* d_in, const int* in_sizes, int n_in,
                              void* d_out, int out_size, void* d_ws, size_t ws_size,
                              hipStream_t stream) {
    const float* latent = (const float*)d_in[0];
    const float* hist = (const float*)d_in[1];
    const float* subg = (const float*)d_in[2];
    const int* eidx = (const int*)d_in[3];
    const float* W1 = (const float*)d_in[4];
    const float* b1 = (const float*)d_in[5];
    const float* W2 = (const float*)d_in[6];
    const float* b2 = (const float*)d_in[7];
    const float* W3 = (const float*)d_in[8];
    const float* b3 = (const float*)d_in[9];
    const float* Wc = (const float*)d_in[10];
    const float* bc = (const float*)d_in[11];
    float* outp = (float*)d_out;

    char* ws = (char*)d_ws;
    size_t off = 0;
    auto take = [&](size_t bytes) -> void* {
        void* p = ws + off;
        off += (bytes + 255) & ~(size_t)255;
        return p;
    };
    float* dinv = (float*)take((size_t)N_NODES * 4);
    int* rs = (int*)take((size_t)N_NODES * 4);
    int* re = (int*)take((size_t)N_NODES * 4);
    int* col = (int*)take((size_t)NBUCK * BCAP * 4);
    u32* entries = (u32*)take((size_t)NBUCK * BCAP * 4);
    int* bcur = (int*)take((size_t)NBUCK * 4);
    __half2* bufH = (__half2*)take((size_t)N_NODES * 128 * 2);  // g1 fp16 [N][64 h2]
    __half2* bufG2 = (__half2*)take((size_t)N_NODES * 64 * 2);  // g2 fp16 [N][32 h2]
    float* bufG3 = (float*)take((size_t)N_NODES * 8 * 4);       // g3 f32 [N][8]
    f16* Wth = (f16*)take((size_t)128 * 256 * 2);               // W1^T hi (k-major)
    f16* Wtl = (f16*)take((size_t)128 * 256 * 2);               // W1^T lo
    f16* W2h = (f16*)take((size_t)64 * 128 * 2);                // W2^T hi (k-major)
    f16* W2l = (f16*)take((size_t)64 * 128 * 2);                // W2^T lo

    const int* srcp = eidx;            // edge_index[0]
    const int* dstp = eidx + N_EDGES;  // edge_index[1]

    const int scat_blocks = (N_EDGES + 8191) / 8192;  // 391

    hipMemsetAsync(bcur, 0, (size_t)NBUCK * 4, stream);
    k_prepw<<<128, 256, 0, stream>>>(W1, Wth, Wtl);
    k_prepw2<<<32, 256, 0, stream>>>(W2, W2h, W2l);
    k_scatter<<<scat_blocks, 256, 0, stream>>>(srcp, dstp, bcur, entries);
    k_prep<<<NBUCK, 256, 0, stream>>>(entries, bcur, rs, re, dinv, col);

    k_gemm1<<<(N_NODES + 255) / 256, 1024, 0, stream>>>(latent, hist, subg, W1, Wth, Wtl, dinv, bufH);
    k_ag2<<<N_NODES / 64, 1024, 0, stream>>>(bufH, rs, re, col, dinv, b1, W2h, W2l, bufG2);
    k_ag3<<<N_NODES / 32, 256, 0, stream>>>(bufG2, rs, re, col, dinv, b2, W3, bufG3);
    k_agf<<<N_NODES / 64, 256, 0, stream>>>(bufG3, rs, re, col, dinv, b3, Wc, bc, outp);
}

// Round 8
// 735.617 us; speedup vs baseline: 1.1397x; 1.1397x over previous
//
#include <hip/hip_runtime.h>
#include <hip/hip_fp16.h>

// 3-layer GCN (fp32 compute): bucketed CSR build + gemm1 + fused
// (aggregate -> GEMM) pairs.
// Round 14: k_prep's per-node src-sort moved from a dynamically-indexed
// private buffer (r13: allocated in SCRATCH -> 97 MB spill writes, prep
// 40->170+ us) to a fully-unrolled 64-element bitonic sorting NETWORK with
// compile-time indices -> pure registers (~1.3k VALU ops/thread, ~4 us
// total). Keeps the sorted-gather benefit (ag2 149->~135: per-XCD row
// re-touches become L2 hits). Everything else identical to r13 (r10 gather
// form, r12 padded-bucket CSR build).

#define N_NODES 200000
#define N_EDGES 3200000
#define NBUCK 782            // ceil(200000/256)
#define BCAP 5120            // padded bucket capacity (mean 4096, +16 sigma)

static_assert(N_NODES % 64 == 0, "tiling");
static_assert((NBUCK - 1) * 256 < N_NODES && NBUCK * 256 >= N_NODES, "buckets");

typedef unsigned int u32;
typedef _Float16 f16;
typedef __attribute__((ext_vector_type(8))) _Float16 f16x8;
typedef __attribute__((ext_vector_type(4))) _Float16 f16x4;
typedef __attribute__((ext_vector_type(4))) float f32x4;
typedef __attribute__((ext_vector_type(2))) float f32x2;

// ------------- chunked scatter: entries[b*BCAP+p] = (src<<8)|dst_local ------
// Block-local histogram, one global atomicAdd per (block,bucket) reserves a
// range in the bucket's padded segment. No global prefix scan needed.

__global__ __launch_bounds__(256) void k_scatter(const int* __restrict__ src,
                                                 const int* __restrict__ dst,
                                                 int* __restrict__ bcur,
                                                 u32* __restrict__ entries) {
    __shared__ int lh[NBUCK];
    __shared__ int base[NBUCK];
    __shared__ int lcur[NBUCK];
    int t = threadIdx.x;
    for (int b = t; b < NBUCK; b += 256) lh[b] = 0;
    __syncthreads();
    long e0 = (long)blockIdx.x * 8192;
    for (int k = 0; k < 32; ++k) {
        long e = e0 + k * 256 + t;
        if (e < N_EDGES) atomicAdd(&lh[dst[e] >> 8], 1);
    }
    __syncthreads();
    for (int b = t; b < NBUCK; b += 256) {
        base[b] = lh[b] ? atomicAdd(&bcur[b], lh[b]) : 0;
        lcur[b] = 0;
    }
    __syncthreads();
    for (int k = 0; k < 32; ++k) {
        long e = e0 + k * 256 + t;
        if (e < N_EDGES) {
            int d = dst[e];
            int bkt = d >> 8;
            int p = base[bkt] + atomicAdd(&lcur[bkt], 1);
            p = p < BCAP ? p : BCAP - 1;  // defensive (cannot trigger w/ fixed input)
            entries[(size_t)bkt * BCAP + p] = ((u32)src[e] << 8) | (u32)(d & 255);
        }
    }
}

// --- per-bucket prep: deg/rs/re/dinv + col fill + per-node src-sort ---------

__global__ __launch_bounds__(256) void k_prep(const u32* __restrict__ entries,
                                              const int* __restrict__ bcur,
                                              int* __restrict__ rs,
                                              int* __restrict__ re,
                                              float* __restrict__ dinv,
                                              int* __restrict__ col) {
    __shared__ int lh[256];
    __shared__ int sc[256];
    __shared__ int cur[256];
    const int b = blockIdx.x, t = threadIdx.x;
    int cnt = bcur[b];
    cnt = cnt < BCAP ? cnt : BCAP;  // defensive
    const u32* ent = entries + (size_t)b * BCAP;
    lh[t] = 0;
    __syncthreads();
    for (int i = t; i < cnt; i += 256) atomicAdd(&lh[ent[i] & 255], 1);
    __syncthreads();
    int my = lh[t];
    sc[t] = my;
    __syncthreads();
    for (int o = 1; o < 256; o <<= 1) {
        int v = (t >= o) ? sc[t - o] : 0;
        __syncthreads();
        sc[t] += v;
        __syncthreads();
    }
    int excl = sc[t] - my;
    int node = b * 256 + t;
    if (node < N_NODES) {
        rs[node] = b * BCAP + excl;
        re[node] = b * BCAP + excl + my;
        dinv[node] = rsqrtf((float)(my + 1));  // +1 self-loop
    }
    cur[t] = b * BCAP + excl;
    __syncthreads();
    for (int i = t; i < cnt; i += 256) {
        u32 en = ent[i];
        int p = atomicAdd(&cur[en & 255], 1);
        col[p] = (int)(en >> 8);
    }
    __syncthreads();  // all col writes visible before the sort re-reads them

    // per-node src-sort: 64-wide bitonic NETWORK, compile-time indices only
    // -> buf lives in registers (r13's dynamic-index version spilled to
    // scratch). Sum is order-invariant; sorted lists give gather L2 hits.
    // deg ~ Poisson(16): P(deg>64) is astronomically small; tail untouched.
    if (node < N_NODES && my > 1) {
        const int base = b * BCAP + excl;
        const int n = my < 64 ? my : 64;
        int buf[64];
#pragma unroll
        for (int i = 0; i < 64; ++i) buf[i] = 0x7fffffff;
#pragma unroll
        for (int i = 0; i < 64; ++i)
            if (i < n) buf[i] = col[base + i];
#pragma unroll
        for (int k = 2; k <= 64; k <<= 1) {
#pragma unroll
            for (int j = k >> 1; j > 0; j >>= 1) {
#pragma unroll
                for (int i = 0; i < 64; ++i) {
                    int l = i ^ j;
                    if (l > i) {
                        int a = buf[i], c = buf[l];
                        if ((i & k) == 0) {
                            buf[i] = a < c ? a : c;
                            buf[l] = a < c ? c : a;
                        } else {
                            buf[i] = a > c ? a : c;
                            buf[l] = a > c ? c : a;
                        }
                    }
                }
            }
        }
#pragma unroll
        for (int i = 0; i < 64; ++i)
            if (i < n) col[base + i] = buf[i];
    }
}

// ------- W1 pre-split/transpose: Wth/Wtl[f][k] f16 hi/lo, k-major -----------

__global__ __launch_bounds__(256) void k_prepw(const float* __restrict__ W,
                                               f16* __restrict__ Wth,
                                               f16* __restrict__ Wtl) {
    int t = blockIdx.x * 256 + threadIdx.x;  // 0..32767
    int k = t >> 7;                          // 0..255 (tail rows 256/257 stay fp32)
    int f = t & 127;
    float w = W[k * 128 + f];
    f16 hi = (f16)w;
    f16 lo = (f16)(w - (float)hi);
    Wth[f * 256 + k] = hi;
    Wtl[f * 256 + k] = lo;
}

// ------- W2 pre-split/transpose: [128][64] -> hi/lo f16 [64][128] k-major ----

__global__ __launch_bounds__(256) void k_prepw2(const float* __restrict__ W2,
                                                f16* __restrict__ Wh,
                                                f16* __restrict__ Wl) {
    int t = blockIdx.x * 256 + threadIdx.x;  // 0..8191
    int k = t >> 6;                          // 0..127
    int f = t & 63;
    float w = W2[k * 64 + f];
    f16 hi = (f16)w;
    Wh[f * 128 + k] = hi;
    Wl[f * 128 + k] = (f16)(w - (float)hi);
}

// ------- GEMM layer 1 (MFMA): [N,258]x[258,128], epilogue g = dinv*h -> fp16
// 1024 threads = 16 waves, 256 nodes/block, 16 nodes/wave. W hi+lo in LDS
// (128 KB, XOR-swizzled), staged once; X fragments global->reg (8 consecutive
// floats/lane); no per-K-step barriers. 3-term split-f16 = ~fp32 precision.

__global__ __launch_bounds__(1024) void k_gemm1(const float* __restrict__ X,
                                                const float* __restrict__ hist,
                                                const float* __restrict__ subg,
                                                const float* __restrict__ W,
                                                const f16* __restrict__ Wth,
                                                const f16* __restrict__ Wtl,
                                                const float* __restrict__ dinv,
                                                __half2* __restrict__ g1) {
    __shared__ f16 Ws[2][128 * 256];   // [hi/lo][row*256+k], byte^((row&7)<<4)
    const int t = threadIdx.x;

    // ---- stage W once (swizzled writes, coalesced global reads) ----
    {
        const int r = t >> 3;          // feat row 0..127
        const int seg = t & 7;         // 32 halves each
        const f16* gh = Wth + r * 256 + seg * 32;
        const f16* gl = Wtl + r * 256 + seg * 32;
        const int sw = (r & 7) << 4;
        const int base = r * 512 + seg * 64;   // byte offset, 16B-granular
        char* wsh = (char*)&Ws[0][0];
        char* wsl = (char*)&Ws[1][0];
#pragma unroll
        for (int q = 0; q < 4; ++q) {
            *(f16x8*)(wsh + ((base + q * 16) ^ sw)) = *(const f16x8*)(gh + q * 8);
            *(f16x8*)(wsl + ((base + q * 16) ^ sw)) = *(const f16x8*)(gl + q * 8);
        }
    }

    const int wv = t >> 6;          // wave 0..15
    const int l = t & 63;
    const int l15 = l & 15;         // node within wave / D column
    const int lk = l >> 4;          // k-chunk 0..3 (8 halves each)
    const int nb = blockIdx.x * 256;
    const int node = nb + wv * 16 + l15;
    const int xrow = node < N_NODES ? node : N_NODES - 1;  // clamp (stores guarded)
    const float* xbase = X + (size_t)xrow * 256 + lk * 8;

    f32x4 acc[8];
#pragma unroll
    for (int fb = 0; fb < 8; ++fb) acc[fb] = (f32x4){0.f, 0.f, 0.f, 0.f};

    // prefetch K-tile 0 (in flight across the staging barrier)
    float4 pa = *(const float4*)(xbase + 0);
    float4 pb = *(const float4*)(xbase + 4);

    __syncthreads();  // W staged -- the only barrier

    const char* wsh = (const char*)&Ws[0][0];
    const char* wsl = (const char*)&Ws[1][0];
    const int sw = (l15 & 7) << 4;  // row&7 == l15&7 for every fb

    for (int kc = 0; kc < 256; kc += 32) {
        float xs[8] = {pa.x, pa.y, pa.z, pa.w, pb.x, pb.y, pb.z, pb.w};
        if (kc + 32 < 256) {  // issue next-tile loads before compute
            pa = *(const float4*)(xbase + kc + 32);
            pb = *(const float4*)(xbase + kc + 36);
        }
        union { f16 h[8]; f16x8 v; } H, L;
#pragma unroll
        for (int i = 0; i < 8; ++i) {
            f16 h = (f16)xs[i];
            H.h[i] = h;
            L.h[i] = (f16)(xs[i] - (float)h);
        }
        f16x8 xh = H.v, xl = L.v;

        const int koff = ((kc + lk * 8) * 2) ^ sw;  // swizzled within-row byte off
#pragma unroll
        for (int fb = 0; fb < 8; ++fb) {
            const int off = (fb * 16 + l15) * 512 + koff;
            f16x8 wh = *(const f16x8*)(wsh + off);
            f16x8 wl = *(const f16x8*)(wsl + off);
            acc[fb] = __builtin_amdgcn_mfma_f32_16x16x32_f16(wh, xh, acc[fb], 0, 0, 0);
            acc[fb] = __builtin_amdgcn_mfma_f32_16x16x32_f16(wh, xl, acc[fb], 0, 0, 0);
            acc[fb] = __builtin_amdgcn_mfma_f32_16x16x32_f16(wl, xh, acc[fb], 0, 0, 0);
        }
    }

    // epilogue: K tail rows 256 (hist), 257 (subg) in exact fp32; scale dinv.
    const bool ok = node < N_NODES;
    const float hh = hist[xrow];
    const float ss = subg[xrow];
    const float dv = dinv[xrow];
    char* orow = (char*)g1 + (size_t)node * 256;
#pragma unroll
    for (int fb = 0; fb < 8; ++fb) {
        const int f0 = fb * 16 + lk * 4;  // 4 consecutive feats per lane
        float4 w6 = *(const float4*)(W + 256 * 128 + f0);
        float4 w7 = *(const float4*)(W + 257 * 128 + f0);
        union { f16 h[4]; float2 v; } o;
        o.h[0] = (f16)((acc[fb][0] + hh * w6.x + ss * w7.x) * dv);
        o.h[1] = (f16)((acc[fb][1] + hh * w6.y + ss * w7.y) * dv);
        o.h[2] = (f16)((acc[fb][2] + hh * w6.z + ss * w7.z) * dv);
        o.h[3] = (f16)((acc[fb][3] + hh * w6.w + ss * w7.w) * dv);
        if (ok) *(float2*)(orow + fb * 32 + lk * 8) = o.v;
    }
}

// ------- fused agg1 + gemm2: h2 = relu(dinv*(sum g1)+b1); g2 = dinv*(h2@W2)
// 1024 threads, 64 nodes/block. Phase A (r10 form): lane owns 4 feats (f16x4,
// 8 B loads), 2 nodes sequentially, 8-deep chunks; src-sorted col gives L2
// locality. Phase B: 16 waves, one 16x16 MFMA tile each (K=128, 3-term split).

__global__ __launch_bounds__(1024) void k_ag2(const __half2* __restrict__ g,
                                              const int* __restrict__ rs,
                                              const int* __restrict__ re,
                                              const int* __restrict__ col,
                                              const float* __restrict__ dinv,
                                              const float* __restrict__ bias,
                                              const f16* __restrict__ W2hg,
                                              const f16* __restrict__ W2lg,
                                              __half2* __restrict__ g2) {
    __shared__ f16 Xh[64][136];
    __shared__ f16 Xl[64][136];
    __shared__ f16 Wh[64][136];
    __shared__ f16 Wl[64][136];
    const int t = threadIdx.x;
    const int nb = blockIdx.x * 64;

    // stage W2 hi/lo (once)
    {
        const int r = t >> 4;          // 0..63
        const int sg = (t & 15) * 8;   // 8 halves
        *(f16x8*)&Wh[r][sg] = *(const f16x8*)(W2hg + r * 128 + sg);
        *(f16x8*)&Wl[r][sg] = *(const f16x8*)(W2lg + r * 128 + sg);
    }

    // ---- phase A: aggregate. lane owns feats 4*ln..+3 of 2 nodes ----
    const int wv = t >> 6;
    const int l = t & 63;
    const int hf = l >> 5;         // 0/1
    const int ln = l & 31;         // f16x4 index within row (32 per row)
    const f16x4* gp = (const f16x4*)g;   // row stride 32 f16x4
    const float4 b4 = *(const float4*)(bias + ln * 4);
    for (int i = 0; i < 2; ++i) {
        const int nloc = wv * 4 + hf * 2 + i;
        const int node = nb + nloc;
        f32x4 a = (f32x4){0.f, 0.f, 0.f, 0.f};
        int idx = rs[node];
        const int e = re[node];
        for (; idx + 8 <= e; idx += 8) {
            u32 off[8];
            f16x4 h[8];
#pragma unroll
            for (int u = 0; u < 8; ++u) off[u] = ((u32)col[idx + u] << 5) + ln;
#pragma unroll
            for (int u = 0; u < 8; ++u) h[u] = gp[off[u]];
#pragma unroll
            for (int u = 0; u < 8; ++u) a += __builtin_convertvector(h[u], f32x4);
        }
        for (; idx < e; ++idx)
            a += __builtin_convertvector(gp[((u32)col[idx] << 5) + ln], f32x4);
        f32x4 fs = __builtin_convertvector(gp[((u32)node << 5) + ln], f32x4);
        const float di = dinv[node];
        float v0 = fmaxf(di * (a[0] + fs[0]) + b4.x, 0.f);
        float v1 = fmaxf(di * (a[1] + fs[1]) + b4.y, 0.f);
        float v2 = fmaxf(di * (a[2] + fs[2]) + b4.z, 0.f);
        float v3 = fmaxf(di * (a[3] + fs[3]) + b4.w, 0.f);
        f16 h0 = (f16)v0, h1 = (f16)v1, h2 = (f16)v2, h3 = (f16)v3;
        f16x4 hi = {h0, h1, h2, h3};
        f16x4 lo = {(f16)(v0 - (float)h0), (f16)(v1 - (float)h1),
                    (f16)(v2 - (float)h2), (f16)(v3 - (float)h3)};
        *(f16x4*)&Xh[nloc][ln * 4] = hi;
        *(f16x4*)&Xl[nloc][ln * 4] = lo;
    }
    __syncthreads();

    // ---- phase B: 16 waves x one 16x16 MFMA tile, K=128 ----
    const int l15 = l & 15;
    const int lk = l >> 4;
    const int nw = wv & 3;    // node tile
    const int fw = wv >> 2;   // feat tile
    f32x4 acc = (f32x4){0.f, 0.f, 0.f, 0.f};
#pragma unroll
    for (int kc = 0; kc < 128; kc += 32) {
        f16x8 xh = *(const f16x8*)&Xh[nw * 16 + l15][kc + lk * 8];
        f16x8 xl = *(const f16x8*)&Xl[nw * 16 + l15][kc + lk * 8];
        f16x8 wh = *(const f16x8*)&Wh[fw * 16 + l15][kc + lk * 8];
        f16x8 wl = *(const f16x8*)&Wl[fw * 16 + l15][kc + lk * 8];
        acc = __builtin_amdgcn_mfma_f32_16x16x32_f16(wh, xh, acc, 0, 0, 0);
        acc = __builtin_amdgcn_mfma_f32_16x16x32_f16(wh, xl, acc, 0, 0, 0);
        acc = __builtin_amdgcn_mfma_f32_16x16x32_f16(wl, xh, acc, 0, 0, 0);
    }
    const int node = nb + nw * 16 + l15;
    const float dv = dinv[node];
    union { f16 h[4]; float2 v; } o;
#pragma unroll
    for (int r = 0; r < 4; ++r) o.h[r] = (f16)(acc[r] * dv);
    *(float2*)((char*)g2 + (size_t)node * 128 + fw * 32 + lk * 8) = o.v;
}

// ------- fused agg2 + gemm3: h3 = relu(dinv*(sum g2)+b2); g3 = dinv*(h3@W3)
// 256 threads, 32 nodes/block. Phase A (r10 form): lane owns 4 feats (f16x4),
// 2 nodes sequentially. Phase B: thread (node,f) 64-MAC dot.

__global__ __launch_bounds__(256) void k_ag3(const __half2* __restrict__ g,
                                             const int* __restrict__ rs,
                                             const int* __restrict__ re,
                                             const int* __restrict__ col,
                                             const float* __restrict__ dinv,
                                             const float* __restrict__ bias,
                                             const float* __restrict__ W3,
                                             float* __restrict__ g3) {
    __shared__ float h3s[32][68];
    __shared__ float W3t[8][68];
    const int t = threadIdx.x;
    const int nb = blockIdx.x * 32;

    for (int i = t; i < 512; i += 256) {
        int k = i & 63, f = i >> 6;
        W3t[f][k] = W3[k * 8 + f];
    }

    const int wv = t >> 6;        // 0..3
    const int l = t & 63;
    const int q = l >> 4;         // 0..3: node-of-quad
    const int ln = l & 15;        // f16x4 index (16 per 64-f16 row)
    const f16x4* gp = (const f16x4*)g;   // row stride 16 f16x4
    const float4 b4 = *(const float4*)(bias + ln * 4);
    for (int i = 0; i < 2; ++i) {
        const int nloc = wv * 8 + q * 2 + i;
        const int node = nb + nloc;
        f32x4 a = (f32x4){0.f, 0.f, 0.f, 0.f};
        int idx = rs[node];
        const int e = re[node];
        for (; idx + 8 <= e; idx += 8) {
            u32 off[8];
            f16x4 h[8];
#pragma unroll
            for (int u = 0; u < 8; ++u) off[u] = ((u32)col[idx + u] << 4) + ln;
#pragma unroll
            for (int u = 0; u < 8; ++u) h[u] = gp[off[u]];
#pragma unroll
            for (int u = 0; u < 8; ++u) a += __builtin_convertvector(h[u], f32x4);
        }
        for (; idx < e; ++idx)
            a += __builtin_convertvector(gp[((u32)col[idx] << 4) + ln], f32x4);
        f32x4 fs = __builtin_convertvector(gp[((u32)node << 4) + ln], f32x4);
        const float di = dinv[node];
        float4 o;
        o.x = fmaxf(di * (a[0] + fs[0]) + b4.x, 0.f);
        o.y = fmaxf(di * (a[1] + fs[1]) + b4.y, 0.f);
        o.z = fmaxf(di * (a[2] + fs[2]) + b4.z, 0.f);
        o.w = fmaxf(di * (a[3] + fs[3]) + b4.w, 0.f);
        *(float4*)&h3s[nloc][ln * 4] = o;
    }
    __syncthreads();

    const int node = t >> 3;   // 0..31
    const int f = t & 7;
    float acc = 0.f;
#pragma unroll
    for (int k4 = 0; k4 < 16; ++k4) {
        float4 x = *(const float4*)&h3s[node][k4 * 4];
        float4 w = *(const float4*)&W3t[f][k4 * 4];
        acc += x.x * w.x + x.y * w.y + x.z * w.z + x.w * w.w;
    }
    g3[(size_t)(nb + node) * 8 + f] = dinv[nb + node] * acc;
}

// ------- fused agg3 + final: h4 = relu(dinv*(sum g3)+b3); out = h4@Wc + bc ---
// 64 nodes/block; lane c=t&3 owns float2 feats 2c..2c+1; 16-deep batches.

__global__ __launch_bounds__(256) void k_agf(const float* __restrict__ g,
                                             const int* __restrict__ rs,
                                             const int* __restrict__ re,
                                             const int* __restrict__ col,
                                             const float* __restrict__ dinv,
                                             const float* __restrict__ bias,
                                             const float* __restrict__ Wc,
                                             const float* __restrict__ bc,
                                             float* __restrict__ out) {
    __shared__ float h4s[64][10];
    __shared__ float Wcs[24];
    __shared__ float bcs[3];
    const int t = threadIdx.x;
    const int nb = blockIdx.x * 64;
    if (t < 24) Wcs[t] = Wc[t];
    if (t < 3) bcs[t] = bc[t];

    const int node = t >> 2;   // 0..63
    const int c = t & 3;       // float2 index within 8-f32 row
    const f32x2* gp = (const f32x2*)g;   // row stride 4 f32x2
    const float2 b2 = *(const float2*)(bias + c * 2);
    f32x2 a = (f32x2){0.f, 0.f};
    const int s = rs[nb + node];
    const int e = re[nb + node];
    int idx = s;
    for (; idx + 16 <= e; idx += 16) {
        u32 off[16];
        f32x2 v[16];
#pragma unroll
        for (int u = 0; u < 16; ++u) off[u] = ((u32)col[idx + u] << 2) + c;
#pragma unroll
        for (int u = 0; u < 16; ++u) v[u] = gp[off[u]];
#pragma unroll
        for (int u = 0; u < 16; ++u) a += v[u];
    }
    for (; idx + 8 <= e; idx += 8) {
        u32 off[8];
        f32x2 v[8];
#pragma unroll
        for (int u = 0; u < 8; ++u) off[u] = ((u32)col[idx + u] << 2) + c;
#pragma unroll
        for (int u = 0; u < 8; ++u) v[u] = gp[off[u]];
#pragma unroll
        for (int u = 0; u < 8; ++u) a += v[u];
    }
    for (; idx < e; ++idx) a += gp[((u32)col[idx] << 2) + c];
    a += gp[((u32)(nb + node) << 2) + c];  // self-loop
    const float di = dinv[nb + node];
    float2 o;
    o.x = fmaxf(di * a[0] + b2.x, 0.f);
    o.y = fmaxf(di * a[1] + b2.y, 0.f);
    *(float2*)&h4s[node][c * 2] = o;
    __syncthreads();

    if ((t & 3) < 3) {
        const int n2 = t >> 2;   // 0..63
        const int cc = t & 3;    // 0..2
        float o2 = bcs[cc];
#pragma unroll
        for (int k = 0; k < 8; ++k) o2 += h4s[n2][k] * Wcs[k * 3 + cc];
        out[(size_t)(nb + n2) * 3 + cc] = o2;
    }
}

// ---------------- launch -----------------------------------------------------

extern "C" void kernel_launch(void* const* d_in, const int* in_sizes, int n_in,
                              void* d_out, int out_size, void* d_ws, size_t ws_size,
                              hipStream_t stream) {
    const float* latent = (const float*)d_in[0];
    const float* hist = (const float*)d_in[1];
    const float* subg = (const float*)d_in[2];
    const int* eidx = (const int*)d_in[3];
    const float* W1 = (const float*)d_in[4];
    const float* b1 = (const float*)d_in[5];
    const float* W2 = (const float*)d_in[6];
    const float* b2 = (const float*)d_in[7];
    const float* W3 = (const float*)d_in[8];
    const float* b3 = (const float*)d_in[9];
    const float* Wc = (const float*)d_in[10];
    const float* bc = (const float*)d_in[11];
    float* outp = (float*)d_out;

    char* ws = (char*)d_ws;
    size_t off = 0;
    auto take = [&](size_t bytes) -> void* {
        void* p = ws + off;
        off += (bytes + 255) & ~(size_t)255;
        return p;
    };
    float* dinv = (float*)take((size_t)N_NODES * 4);
    int* rs = (int*)take((size_t)N_NODES * 4);
    int* re = (int*)take((size_t)N_NODES * 4);
    int* col = (int*)take((size_t)NBUCK * BCAP * 4);
    u32* entries = (u32*)take((size_t)NBUCK * BCAP * 4);
    int* bcur = (int*)take((size_t)NBUCK * 4);
    __half2* bufH = (__half2*)take((size_t)N_NODES * 128 * 2);  // g1 fp16 [N][64 h2]
    __half2* bufG2 = (__half2*)take((size_t)N_NODES * 64 * 2);  // g2 fp16 [N][32 h2]
    float* bufG3 = (float*)take((size_t)N_NODES * 8 * 4);       // g3 f32 [N][8]
    f16* Wth = (f16*)take((size_t)128 * 256 * 2);               // W1^T hi (k-major)
    f16* Wtl = (f16*)take((size_t)128 * 256 * 2);               // W1^T lo
    f16* W2h = (f16*)take((size_t)64 * 128 * 2);                // W2^T hi (k-major)
    f16* W2l = (f16*)take((size_t)64 * 128 * 2);                // W2^T lo

    const int* srcp = eidx;            // edge_index[0]
    const int* dstp = eidx + N_EDGES;  // edge_index[1]

    const int scat_blocks = (N_EDGES + 8191) / 8192;  // 391

    hipMemsetAsync(bcur, 0, (size_t)NBUCK * 4, stream);
    k_prepw<<<128, 256, 0, stream>>>(W1, Wth, Wtl);
    k_prepw2<<<32, 256, 0, stream>>>(W2, W2h, W2l);
    k_scatter<<<scat_blocks, 256, 0, stream>>>(srcp, dstp, bcur, entries);
    k_prep<<<NBUCK, 256, 0, stream>>>(entries, bcur, rs, re, dinv, col);

    k_gemm1<<<(N_NODES + 255) / 256, 1024, 0, stream>>>(latent, hist, subg, W1, Wth, Wtl, dinv, bufH);
    k_ag2<<<N_NODES / 64, 1024, 0, stream>>>(bufH, rs, re, col, dinv, b1, W2h, W2l, bufG2);
    k_ag3<<<N_NODES / 32, 256, 0, stream>>>(bufG2, rs, re, col, dinv, b2, W3, bufG3);
    k_agf<<<N_NODES / 64, 256, 0, stream>>>(bufG3, rs, re, col, dinv, b3, Wc, bc, outp);
}

// Round 9
// 711.958 us; speedup vs baseline: 1.1775x; 1.0332x over previous
//
#include <hip/hip_runtime.h>
#include <hip/hip_fp16.h>

// 3-layer GCN (fp32 compute): bucketed CSR build + gemm1 + fused
// (aggregate -> GEMM) pairs.
// Round 15: drop the per-node src-sort entirely. r14 counters REFUTED the
// locality theory: ag2 FETCH 406.4 MB bit-identical sorted vs unsorted,
// dur 147.6 vs 148.7 (noise) -- a ~16-entry list spanning 0..200k doesn't
// narrow the hot src window. The bitonic pass was ~40-50 us of pure cost.
// k_prep reverts to the r12 form (padded-bucket build, no bhist/bscan).
// k_ag2 is at its compulsory-traffic floor: 8 XCDs x 51.2 MB L3-resident
// table at ~3 TB/s L2-miss-path delivery; occupancy maxed; VALU slimming
// (r10), 2x MLP (r12), sorting (r14) all proven non-levers.

#define N_NODES 200000
#define N_EDGES 3200000
#define NBUCK 782            // ceil(200000/256)
#define BCAP 5120            // padded bucket capacity (mean 4096, +16 sigma)

static_assert(N_NODES % 64 == 0, "tiling");
static_assert((NBUCK - 1) * 256 < N_NODES && NBUCK * 256 >= N_NODES, "buckets");

typedef unsigned int u32;
typedef _Float16 f16;
typedef __attribute__((ext_vector_type(8))) _Float16 f16x8;
typedef __attribute__((ext_vector_type(4))) _Float16 f16x4;
typedef __attribute__((ext_vector_type(4))) float f32x4;
typedef __attribute__((ext_vector_type(2))) float f32x2;

// ------------- chunked scatter: entries[b*BCAP+p] = (src<<8)|dst_local ------
// Block-local histogram, one global atomicAdd per (block,bucket) reserves a
// range in the bucket's padded segment. No global prefix scan needed.

__global__ __launch_bounds__(256) void k_scatter(const int* __restrict__ src,
                                                 const int* __restrict__ dst,
                                                 int* __restrict__ bcur,
                                                 u32* __restrict__ entries) {
    __shared__ int lh[NBUCK];
    __shared__ int base[NBUCK];
    __shared__ int lcur[NBUCK];
    int t = threadIdx.x;
    for (int b = t; b < NBUCK; b += 256) lh[b] = 0;
    __syncthreads();
    long e0 = (long)blockIdx.x * 8192;
    for (int k = 0; k < 32; ++k) {
        long e = e0 + k * 256 + t;
        if (e < N_EDGES) atomicAdd(&lh[dst[e] >> 8], 1);
    }
    __syncthreads();
    for (int b = t; b < NBUCK; b += 256) {
        base[b] = lh[b] ? atomicAdd(&bcur[b], lh[b]) : 0;
        lcur[b] = 0;
    }
    __syncthreads();
    for (int k = 0; k < 32; ++k) {
        long e = e0 + k * 256 + t;
        if (e < N_EDGES) {
            int d = dst[e];
            int bkt = d >> 8;
            int p = base[bkt] + atomicAdd(&lcur[bkt], 1);
            p = p < BCAP ? p : BCAP - 1;  // defensive (cannot trigger w/ fixed input)
            entries[(size_t)bkt * BCAP + p] = ((u32)src[e] << 8) | (u32)(d & 255);
        }
    }
}

// --- per-bucket prep: deg/rs/re/dinv + col fill, all L2-local to one block --

__global__ __launch_bounds__(256) void k_prep(const u32* __restrict__ entries,
                                              const int* __restrict__ bcur,
                                              int* __restrict__ rs,
                                              int* __restrict__ re,
                                              float* __restrict__ dinv,
                                              int* __restrict__ col) {
    __shared__ int lh[256];
    __shared__ int sc[256];
    __shared__ int cur[256];
    const int b = blockIdx.x, t = threadIdx.x;
    int cnt = bcur[b];
    cnt = cnt < BCAP ? cnt : BCAP;  // defensive
    const u32* ent = entries + (size_t)b * BCAP;
    lh[t] = 0;
    __syncthreads();
    for (int i = t; i < cnt; i += 256) atomicAdd(&lh[ent[i] & 255], 1);
    __syncthreads();
    int my = lh[t];
    sc[t] = my;
    __syncthreads();
    for (int o = 1; o < 256; o <<= 1) {
        int v = (t >= o) ? sc[t - o] : 0;
        __syncthreads();
        sc[t] += v;
        __syncthreads();
    }
    int excl = sc[t] - my;
    int node = b * 256 + t;
    if (node < N_NODES) {
        rs[node] = b * BCAP + excl;
        re[node] = b * BCAP + excl + my;
        dinv[node] = rsqrtf((float)(my + 1));  // +1 self-loop
    }
    cur[t] = b * BCAP + excl;
    __syncthreads();
    for (int i = t; i < cnt; i += 256) {
        u32 en = ent[i];
        int p = atomicAdd(&cur[en & 255], 1);
        col[p] = (int)(en >> 8);
    }
}

// ------- W1 pre-split/transpose: Wth/Wtl[f][k] f16 hi/lo, k-major -----------

__global__ __launch_bounds__(256) void k_prepw(const float* __restrict__ W,
                                               f16* __restrict__ Wth,
                                               f16* __restrict__ Wtl) {
    int t = blockIdx.x * 256 + threadIdx.x;  // 0..32767
    int k = t >> 7;                          // 0..255 (tail rows 256/257 stay fp32)
    int f = t & 127;
    float w = W[k * 128 + f];
    f16 hi = (f16)w;
    f16 lo = (f16)(w - (float)hi);
    Wth[f * 256 + k] = hi;
    Wtl[f * 256 + k] = lo;
}

// ------- W2 pre-split/transpose: [128][64] -> hi/lo f16 [64][128] k-major ----

__global__ __launch_bounds__(256) void k_prepw2(const float* __restrict__ W2,
                                                f16* __restrict__ Wh,
                                                f16* __restrict__ Wl) {
    int t = blockIdx.x * 256 + threadIdx.x;  // 0..8191
    int k = t >> 6;                          // 0..127
    int f = t & 63;
    float w = W2[k * 64 + f];
    f16 hi = (f16)w;
    Wh[f * 128 + k] = hi;
    Wl[f * 128 + k] = (f16)(w - (float)hi);
}

// ------- GEMM layer 1 (MFMA): [N,258]x[258,128], epilogue g = dinv*h -> fp16
// 1024 threads = 16 waves, 256 nodes/block, 16 nodes/wave. W hi+lo in LDS
// (128 KB, XOR-swizzled), staged once; X fragments global->reg (8 consecutive
// floats/lane); no per-K-step barriers. 3-term split-f16 = ~fp32 precision.

__global__ __launch_bounds__(1024) void k_gemm1(const float* __restrict__ X,
                                                const float* __restrict__ hist,
                                                const float* __restrict__ subg,
                                                const float* __restrict__ W,
                                                const f16* __restrict__ Wth,
                                                const f16* __restrict__ Wtl,
                                                const float* __restrict__ dinv,
                                                __half2* __restrict__ g1) {
    __shared__ f16 Ws[2][128 * 256];   // [hi/lo][row*256+k], byte^((row&7)<<4)
    const int t = threadIdx.x;

    // ---- stage W once (swizzled writes, coalesced global reads) ----
    {
        const int r = t >> 3;          // feat row 0..127
        const int seg = t & 7;         // 32 halves each
        const f16* gh = Wth + r * 256 + seg * 32;
        const f16* gl = Wtl + r * 256 + seg * 32;
        const int sw = (r & 7) << 4;
        const int base = r * 512 + seg * 64;   // byte offset, 16B-granular
        char* wsh = (char*)&Ws[0][0];
        char* wsl = (char*)&Ws[1][0];
#pragma unroll
        for (int q = 0; q < 4; ++q) {
            *(f16x8*)(wsh + ((base + q * 16) ^ sw)) = *(const f16x8*)(gh + q * 8);
            *(f16x8*)(wsl + ((base + q * 16) ^ sw)) = *(const f16x8*)(gl + q * 8);
        }
    }

    const int wv = t >> 6;          // wave 0..15
    const int l = t & 63;
    const int l15 = l & 15;         // node within wave / D column
    const int lk = l >> 4;          // k-chunk 0..3 (8 halves each)
    const int nb = blockIdx.x * 256;
    const int node = nb + wv * 16 + l15;
    const int xrow = node < N_NODES ? node : N_NODES - 1;  // clamp (stores guarded)
    const float* xbase = X + (size_t)xrow * 256 + lk * 8;

    f32x4 acc[8];
#pragma unroll
    for (int fb = 0; fb < 8; ++fb) acc[fb] = (f32x4){0.f, 0.f, 0.f, 0.f};

    // prefetch K-tile 0 (in flight across the staging barrier)
    float4 pa = *(const float4*)(xbase + 0);
    float4 pb = *(const float4*)(xbase + 4);

    __syncthreads();  // W staged -- the only barrier

    const char* wsh = (const char*)&Ws[0][0];
    const char* wsl = (const char*)&Ws[1][0];
    const int sw = (l15 & 7) << 4;  // row&7 == l15&7 for every fb

    for (int kc = 0; kc < 256; kc += 32) {
        float xs[8] = {pa.x, pa.y, pa.z, pa.w, pb.x, pb.y, pb.z, pb.w};
        if (kc + 32 < 256) {  // issue next-tile loads before compute
            pa = *(const float4*)(xbase + kc + 32);
            pb = *(const float4*)(xbase + kc + 36);
        }
        union { f16 h[8]; f16x8 v; } H, L;
#pragma unroll
        for (int i = 0; i < 8; ++i) {
            f16 h = (f16)xs[i];
            H.h[i] = h;
            L.h[i] = (f16)(xs[i] - (float)h);
        }
        f16x8 xh = H.v, xl = L.v;

        const int koff = ((kc + lk * 8) * 2) ^ sw;  // swizzled within-row byte off
#pragma unroll
        for (int fb = 0; fb < 8; ++fb) {
            const int off = (fb * 16 + l15) * 512 + koff;
            f16x8 wh = *(const f16x8*)(wsh + off);
            f16x8 wl = *(const f16x8*)(wsl + off);
            acc[fb] = __builtin_amdgcn_mfma_f32_16x16x32_f16(wh, xh, acc[fb], 0, 0, 0);
            acc[fb] = __builtin_amdgcn_mfma_f32_16x16x32_f16(wh, xl, acc[fb], 0, 0, 0);
            acc[fb] = __builtin_amdgcn_mfma_f32_16x16x32_f16(wl, xh, acc[fb], 0, 0, 0);
        }
    }

    // epilogue: K tail rows 256 (hist), 257 (subg) in exact fp32; scale dinv.
    const bool ok = node < N_NODES;
    const float hh = hist[xrow];
    const float ss = subg[xrow];
    const float dv = dinv[xrow];
    char* orow = (char*)g1 + (size_t)node * 256;
#pragma unroll
    for (int fb = 0; fb < 8; ++fb) {
        const int f0 = fb * 16 + lk * 4;  // 4 consecutive feats per lane
        float4 w6 = *(const float4*)(W + 256 * 128 + f0);
        float4 w7 = *(const float4*)(W + 257 * 128 + f0);
        union { f16 h[4]; float2 v; } o;
        o.h[0] = (f16)((acc[fb][0] + hh * w6.x + ss * w7.x) * dv);
        o.h[1] = (f16)((acc[fb][1] + hh * w6.y + ss * w7.y) * dv);
        o.h[2] = (f16)((acc[fb][2] + hh * w6.z + ss * w7.z) * dv);
        o.h[3] = (f16)((acc[fb][3] + hh * w6.w + ss * w7.w) * dv);
        if (ok) *(float2*)(orow + fb * 32 + lk * 8) = o.v;
    }
}

// ------- fused agg1 + gemm2: h2 = relu(dinv*(sum g1)+b1); g2 = dinv*(h2@W2)
// 1024 threads, 64 nodes/block. Phase A (r10 form): lane owns 4 feats (f16x4,
// 8 B loads), 2 nodes sequentially, 8-deep chunks. Phase B: 16 waves, one
// 16x16 MFMA tile each (K=128, 3-term split-f16).

__global__ __launch_bounds__(1024) void k_ag2(const __half2* __restrict__ g,
                                              const int* __restrict__ rs,
                                              const int* __restrict__ re,
                                              const int* __restrict__ col,
                                              const float* __restrict__ dinv,
                                              const float* __restrict__ bias,
                                              const f16* __restrict__ W2hg,
                                              const f16* __restrict__ W2lg,
                                              __half2* __restrict__ g2) {
    __shared__ f16 Xh[64][136];
    __shared__ f16 Xl[64][136];
    __shared__ f16 Wh[64][136];
    __shared__ f16 Wl[64][136];
    const int t = threadIdx.x;
    const int nb = blockIdx.x * 64;

    // stage W2 hi/lo (once)
    {
        const int r = t >> 4;          // 0..63
        const int sg = (t & 15) * 8;   // 8 halves
        *(f16x8*)&Wh[r][sg] = *(const f16x8*)(W2hg + r * 128 + sg);
        *(f16x8*)&Wl[r][sg] = *(const f16x8*)(W2lg + r * 128 + sg);
    }

    // ---- phase A: aggregate. lane owns feats 4*ln..+3 of 2 nodes ----
    const int wv = t >> 6;
    const int l = t & 63;
    const int hf = l >> 5;         // 0/1
    const int ln = l & 31;         // f16x4 index within row (32 per row)
    const f16x4* gp = (const f16x4*)g;   // row stride 32 f16x4
    const float4 b4 = *(const float4*)(bias + ln * 4);
    for (int i = 0; i < 2; ++i) {
        const int nloc = wv * 4 + hf * 2 + i;
        const int node = nb + nloc;
        f32x4 a = (f32x4){0.f, 0.f, 0.f, 0.f};
        int idx = rs[node];
        const int e = re[node];
        for (; idx + 8 <= e; idx += 8) {
            u32 off[8];
            f16x4 h[8];
#pragma unroll
            for (int u = 0; u < 8; ++u) off[u] = ((u32)col[idx + u] << 5) + ln;
#pragma unroll
            for (int u = 0; u < 8; ++u) h[u] = gp[off[u]];
#pragma unroll
            for (int u = 0; u < 8; ++u) a += __builtin_convertvector(h[u], f32x4);
        }
        for (; idx < e; ++idx)
            a += __builtin_convertvector(gp[((u32)col[idx] << 5) + ln], f32x4);
        f32x4 fs = __builtin_convertvector(gp[((u32)node << 5) + ln], f32x4);
        const float di = dinv[node];
        float v0 = fmaxf(di * (a[0] + fs[0]) + b4.x, 0.f);
        float v1 = fmaxf(di * (a[1] + fs[1]) + b4.y, 0.f);
        float v2 = fmaxf(di * (a[2] + fs[2]) + b4.z, 0.f);
        float v3 = fmaxf(di * (a[3] + fs[3]) + b4.w, 0.f);
        f16 h0 = (f16)v0, h1 = (f16)v1, h2 = (f16)v2, h3 = (f16)v3;
        f16x4 hi = {h0, h1, h2, h3};
        f16x4 lo = {(f16)(v0 - (float)h0), (f16)(v1 - (float)h1),
                    (f16)(v2 - (float)h2), (f16)(v3 - (float)h3)};
        *(f16x4*)&Xh[nloc][ln * 4] = hi;
        *(f16x4*)&Xl[nloc][ln * 4] = lo;
    }
    __syncthreads();

    // ---- phase B: 16 waves x one 16x16 MFMA tile, K=128 ----
    const int l15 = l & 15;
    const int lk = l >> 4;
    const int nw = wv & 3;    // node tile
    const int fw = wv >> 2;   // feat tile
    f32x4 acc = (f32x4){0.f, 0.f, 0.f, 0.f};
#pragma unroll
    for (int kc = 0; kc < 128; kc += 32) {
        f16x8 xh = *(const f16x8*)&Xh[nw * 16 + l15][kc + lk * 8];
        f16x8 xl = *(const f16x8*)&Xl[nw * 16 + l15][kc + lk * 8];
        f16x8 wh = *(const f16x8*)&Wh[fw * 16 + l15][kc + lk * 8];
        f16x8 wl = *(const f16x8*)&Wl[fw * 16 + l15][kc + lk * 8];
        acc = __builtin_amdgcn_mfma_f32_16x16x32_f16(wh, xh, acc, 0, 0, 0);
        acc = __builtin_amdgcn_mfma_f32_16x16x32_f16(wh, xl, acc, 0, 0, 0);
        acc = __builtin_amdgcn_mfma_f32_16x16x32_f16(wl, xh, acc, 0, 0, 0);
    }
    const int node = nb + nw * 16 + l15;
    const float dv = dinv[node];
    union { f16 h[4]; float2 v; } o;
#pragma unroll
    for (int r = 0; r < 4; ++r) o.h[r] = (f16)(acc[r] * dv);
    *(float2*)((char*)g2 + (size_t)node * 128 + fw * 32 + lk * 8) = o.v;
}

// ------- fused agg2 + gemm3: h3 = relu(dinv*(sum g2)+b2); g3 = dinv*(h3@W3)
// 256 threads, 32 nodes/block. Phase A (r10 form): lane owns 4 feats (f16x4),
// 2 nodes sequentially. Phase B: thread (node,f) 64-MAC dot.

__global__ __launch_bounds__(256) void k_ag3(const __half2* __restrict__ g,
                                             const int* __restrict__ rs,
                                             const int* __restrict__ re,
                                             const int* __restrict__ col,
                                             const float* __restrict__ dinv,
                                             const float* __restrict__ bias,
                                             const float* __restrict__ W3,
                                             float* __restrict__ g3) {
    __shared__ float h3s[32][68];
    __shared__ float W3t[8][68];
    const int t = threadIdx.x;
    const int nb = blockIdx.x * 32;

    for (int i = t; i < 512; i += 256) {
        int k = i & 63, f = i >> 6;
        W3t[f][k] = W3[k * 8 + f];
    }

    const int wv = t >> 6;        // 0..3
    const int l = t & 63;
    const int q = l >> 4;         // 0..3: node-of-quad
    const int ln = l & 15;        // f16x4 index (16 per 64-f16 row)
    const f16x4* gp = (const f16x4*)g;   // row stride 16 f16x4
    const float4 b4 = *(const float4*)(bias + ln * 4);
    for (int i = 0; i < 2; ++i) {
        const int nloc = wv * 8 + q * 2 + i;
        const int node = nb + nloc;
        f32x4 a = (f32x4){0.f, 0.f, 0.f, 0.f};
        int idx = rs[node];
        const int e = re[node];
        for (; idx + 8 <= e; idx += 8) {
            u32 off[8];
            f16x4 h[8];
#pragma unroll
            for (int u = 0; u < 8; ++u) off[u] = ((u32)col[idx + u] << 4) + ln;
#pragma unroll
            for (int u = 0; u < 8; ++u) h[u] = gp[off[u]];
#pragma unroll
            for (int u = 0; u < 8; ++u) a += __builtin_convertvector(h[u], f32x4);
        }
        for (; idx < e; ++idx)
            a += __builtin_convertvector(gp[((u32)col[idx] << 4) + ln], f32x4);
        f32x4 fs = __builtin_convertvector(gp[((u32)node << 4) + ln], f32x4);
        const float di = dinv[node];
        float4 o;
        o.x = fmaxf(di * (a[0] + fs[0]) + b4.x, 0.f);
        o.y = fmaxf(di * (a[1] + fs[1]) + b4.y, 0.f);
        o.z = fmaxf(di * (a[2] + fs[2]) + b4.z, 0.f);
        o.w = fmaxf(di * (a[3] + fs[3]) + b4.w, 0.f);
        *(float4*)&h3s[nloc][ln * 4] = o;
    }
    __syncthreads();

    const int node = t >> 3;   // 0..31
    const int f = t & 7;
    float acc = 0.f;
#pragma unroll
    for (int k4 = 0; k4 < 16; ++k4) {
        float4 x = *(const float4*)&h3s[node][k4 * 4];
        float4 w = *(const float4*)&W3t[f][k4 * 4];
        acc += x.x * w.x + x.y * w.y + x.z * w.z + x.w * w.w;
    }
    g3[(size_t)(nb + node) * 8 + f] = dinv[nb + node] * acc;
}

// ------- fused agg3 + final: h4 = relu(dinv*(sum g3)+b3); out = h4@Wc + bc ---
// 64 nodes/block; lane c=t&3 owns float2 feats 2c..2c+1; 16-deep batches.

__global__ __launch_bounds__(256) void k_agf(const float* __restrict__ g,
                                             const int* __restrict__ rs,
                                             const int* __restrict__ re,
                                             const int* __restrict__ col,
                                             const float* __restrict__ dinv,
                                             const float* __restrict__ bias,
                                             const float* __restrict__ Wc,
                                             const float* __restrict__ bc,
                                             float* __restrict__ out) {
    __shared__ float h4s[64][10];
    __shared__ float Wcs[24];
    __shared__ float bcs[3];
    const int t = threadIdx.x;
    const int nb = blockIdx.x * 64;
    if (t < 24) Wcs[t] = Wc[t];
    if (t < 3) bcs[t] = bc[t];

    const int node = t >> 2;   // 0..63
    const int c = t & 3;       // float2 index within 8-f32 row
    const f32x2* gp = (const f32x2*)g;   // row stride 4 f32x2
    const float2 b2 = *(const float2*)(bias + c * 2);
    f32x2 a = (f32x2){0.f, 0.f};
    const int s = rs[nb + node];
    const int e = re[nb + node];
    int idx = s;
    for (; idx + 16 <= e; idx += 16) {
        u32 off[16];
        f32x2 v[16];
#pragma unroll
        for (int u = 0; u < 16; ++u) off[u] = ((u32)col[idx + u] << 2) + c;
#pragma unroll
        for (int u = 0; u < 16; ++u) v[u] = gp[off[u]];
#pragma unroll
        for (int u = 0; u < 16; ++u) a += v[u];
    }
    for (; idx + 8 <= e; idx += 8) {
        u32 off[8];
        f32x2 v[8];
#pragma unroll
        for (int u = 0; u < 8; ++u) off[u] = ((u32)col[idx + u] << 2) + c;
#pragma unroll
        for (int u = 0; u < 8; ++u) v[u] = gp[off[u]];
#pragma unroll
        for (int u = 0; u < 8; ++u) a += v[u];
    }
    for (; idx < e; ++idx) a += gp[((u32)col[idx] << 2) + c];
    a += gp[((u32)(nb + node) << 2) + c];  // self-loop
    const float di = dinv[nb + node];
    float2 o;
    o.x = fmaxf(di * a[0] + b2.x, 0.f);
    o.y = fmaxf(di * a[1] + b2.y, 0.f);
    *(float2*)&h4s[node][c * 2] = o;
    __syncthreads();

    if ((t & 3) < 3) {
        const int n2 = t >> 2;   // 0..63
        const int cc = t & 3;    // 0..2
        float o2 = bcs[cc];
#pragma unroll
        for (int k = 0; k < 8; ++k) o2 += h4s[n2][k] * Wcs[k * 3 + cc];
        out[(size_t)(nb + n2) * 3 + cc] = o2;
    }
}

// ---------------- launch -----------------------------------------------------

extern "C" void kernel_launch(void* const* d_in, const int* in_sizes, int n_in,
                              void* d_out, int out_size, void* d_ws, size_t ws_size,
                              hipStream_t stream) {
    const float* latent = (const float*)d_in[0];
    const float* hist = (const float*)d_in[1];
    const float* subg = (const float*)d_in[2];
    const int* eidx = (const int*)d_in[3];
    const float* W1 = (const float*)d_in[4];
    const float* b1 = (const float*)d_in[5];
    const float* W2 = (const float*)d_in[6];
    const float* b2 = (const float*)d_in[7];
    const float* W3 = (const float*)d_in[8];
    const float* b3 = (const float*)d_in[9];
    const float* Wc = (const float*)d_in[10];
    const float* bc = (const float*)d_in[11];
    float* outp = (float*)d_out;

    char* ws = (char*)d_ws;
    size_t off = 0;
    auto take = [&](size_t bytes) -> void* {
        void* p = ws + off;
        off += (bytes + 255) & ~(size_t)255;
        return p;
    };
    float* dinv = (float*)take((size_t)N_NODES * 4);
    int* rs = (int*)take((size_t)N_NODES * 4);
    int* re = (int*)take((size_t)N_NODES * 4);
    int* col = (int*)take((size_t)NBUCK * BCAP * 4);
    u32* entries = (u32*)take((size_t)NBUCK * BCAP * 4);
    int* bcur = (int*)take((size_t)NBUCK * 4);
    __half2* bufH = (__half2*)take((size_t)N_NODES * 128 * 2);  // g1 fp16 [N][64 h2]
    __half2* bufG2 = (__half2*)take((size_t)N_NODES * 64 * 2);  // g2 fp16 [N][32 h2]
    float* bufG3 = (float*)take((size_t)N_NODES * 8 * 4);       // g3 f32 [N][8]
    f16* Wth = (f16*)take((size_t)128 * 256 * 2);               // W1^T hi (k-major)
    f16* Wtl = (f16*)take((size_t)128 * 256 * 2);               // W1^T lo
    f16* W2h = (f16*)take((size_t)64 * 128 * 2);                // W2^T hi (k-major)
    f16* W2l = (f16*)take((size_t)64 * 128 * 2);                // W2^T lo

    const int* srcp = eidx;            // edge_index[0]
    const int* dstp = eidx + N_EDGES;  // edge_index[1]

    const int scat_blocks = (N_EDGES + 8191) / 8192;  // 391

    hipMemsetAsync(bcur, 0, (size_t)NBUCK * 4, stream);
    k_prepw<<<128, 256, 0, stream>>>(W1, Wth, Wtl);
    k_prepw2<<<32, 256, 0, stream>>>(W2, W2h, W2l);
    k_scatter<<<scat_blocks, 256, 0, stream>>>(srcp, dstp, bcur, entries);
    k_prep<<<NBUCK, 256, 0, stream>>>(entries, bcur, rs, re, dinv, col);

    k_gemm1<<<(N_NODES + 255) / 256, 1024, 0, stream>>>(latent, hist, subg, W1, Wth, Wtl, dinv, bufH);
    k_ag2<<<N_NODES / 64, 1024, 0, stream>>>(bufH, rs, re, col, dinv, b1, W2h, W2l, bufG2);
    k_ag3<<<N_NODES / 32, 256, 0, stream>>>(bufG2, rs, re, col, dinv, b2, W3, bufG3);
    k_agf<<<N_NODES / 64, 256, 0, stream>>>(bufG3, rs, re, col, dinv, b3, Wc, bc, outp);
}